// Round 8
// baseline (102.045 us; speedup 1.0000x reference)
//
#include <hip/hip_runtime.h>

// ACT-R activation recurrence, v6: block-cooperative 8-cols/block, 8 blocks/CU.
// m[i] = log( sum_{j<i} ((sp_i-sp_j)*86400*h)^(-(c*exp(m_j)+a)) ), m[0]=-inf
// out[i-1] = 1/(1+exp((tau-m[i])/s)).  exp(m_j)==sum_j => nd_j = -(c*sum_j+a).
// (clamp dropped: diffs >= 0.1*86400*0.025 = 216 >> 1; nd < -a always.)
//
// Block: 256 thr = 4 waves, 8 cols (4 pairs). Lane = d(0..15) x pair(0..3),
// v2f per lane. Grid 2048 -> 8 blocks/CU -> 32 waves/CU (8/SIMD).
// Per tile T=16:
//  rect:   wave wv handles j ≡ wv (mod 4), j<i0; lane (d,pair) accumulates v2f;
//          partials -> rbuf (no shuffle reduce needed).
//  logs:   all 4 waves compute next tile's 480 v2f triangle logs into
//          ltri[buf^1] (decay-independent).  barrier1.
//  tri:    WAVE 0 ONLY resolves all 8 cols: 15 steps, bpermute broadcast of
//          nd_j from lane 16*pair+j; sentinel L=1e9 kills d<=j terms
//          (exp2(nd*1e9)=0, nd<0 always); writes nd + sigmoid out.  barrier2.

typedef float v2f __attribute__((ext_vector_type(2)));
typedef float v4f __attribute__((ext_vector_type(4)));

constexpr int S    = 128;
constexpr int B    = 16384;
constexpr int T    = 16;
constexpr int CPB  = 8;     // cols per block (4 pairs)
constexpr int RSTR = 20;    // floats/row: 4 quads (sp0,sp1,nd0,nd1) + 4 pad
constexpr int LTS  = 960;   // floats per ltri buffer: 120 slots x (4 pairs x v2f)

__launch_bounds__(256, 8)
__global__ void actr_kernel(const float* __restrict__ sp,
                            const float* __restrict__ w,
                            float* __restrict__ out) {
    __shared__ float spnd[S * RSTR];   // 10240 B
    __shared__ float ltri[2 * LTS];    //  7680 B
    __shared__ float rbuf[4 * 128];    //  2048 B   (total 19968 B)

    const int tid  = threadIdx.x;
    const int wv   = tid >> 6;            // rect j-residue / triangle-owner flag
    const int lane = tid & 63;
    const int d    = lane & 15;
    const int pr   = lane >> 4;           // pair 0..3
    const int qoff = 4 * pr;
    const int gc0  = blockIdx.x * CPB;

    const float a = w[0], c = w[1], sv = w[2], tau = w[3], h = w[4];
    const float scale = 86400.0f * h;
    const float k_out = 1.44269504088896f / sv;   // log2(e)/s
    const float ln2   = 0.693147180559945f;

    // ---- stage sp*scale; row0 nd = -a; sentinel pair in row0 pad
    for (int idx = tid; idx < S * CPB; idx += 256) {
        const int j = idx >> 3, cc = idx & 7;
        spnd[j * RSTR + 4 * (cc >> 1) + (cc & 1)] = sp[j * B + gc0 + cc] * scale;
    }
    if (tid < CPB) spnd[4 * (tid >> 1) + 2 + (tid & 1)] = -a;
    if (tid < 2)   spnd[16 + tid] = 1.0e9f;

    // ---- decode 2 log tasks: ids tid and tid+256 (of 480 = 120 slots x 4 pairs)
    int ro1d, ro1j, dst1, ro2d = 0, ro2j = 0, dst2 = 0;
    {
        int g = tid;
        #pragma unroll
        for (int k = 0; k < 2; ++k) {
            const int p = g >> 2, q = g & 3;
            int t = (int)((1.0f + __builtin_sqrtf(1.0f + 8.0f * (float)p)) * 0.5f);
            while (t * (t - 1) / 2 > p) --t;
            while ((t + 1) * t / 2 <= p) ++t;
            const int dd = t, jj = p - t * (t - 1) / 2;   // slot (dd,jj), jj<dd
            const int rd = dd * RSTR + 4 * q, rj = jj * RSTR + 4 * q;
            const int ds = p * 8 + 2 * q;
            if (k == 0) { ro1d = rd; ro1j = rj; dst1 = ds; }
            else        { ro2d = rd; ro2j = rj; dst2 = ds; }
            g += 256;
        }
    }
    const bool ok2 = tid < (480 - 256);
    __syncthreads();

    // ---- prologue: logs for tile 0 into buf 0 (visible after barrier1 of tile 0)
    {
        const v2f A = *(const v2f*)&spnd[ro1d] - *(const v2f*)&spnd[ro1j];
        *(v2f*)&ltri[dst1] =
            (v2f){__builtin_amdgcn_logf(A.x), __builtin_amdgcn_logf(A.y)};
        if (ok2) {
            const v2f Bv = *(const v2f*)&spnd[ro2d] - *(const v2f*)&spnd[ro2j];
            *(v2f*)&ltri[dst2] =
                (v2f){__builtin_amdgcn_logf(Bv.x), __builtin_amdgcn_logf(Bv.y)};
        }
    }

    const int   bpa     = (lane & 0x30) * 4;        // bpermute byte base (lane 16*pr)
    const int   tribase = d * (d - 1) * 4 + 2 * pr; // (bp)*8 + 2*pr
    const float* sent   = &spnd[16];
    int buf = 0;

    for (int i0 = 0; i0 < S; i0 += T) {
        // ---- rect: i = i0+d, j ≡ wv (mod 4), j < i0 (quad = sp.xy nd.zw)
        const v2f spi = *(const v2f*)&spnd[(i0 + d) * RSTR + qoff];
        v2f r = {0.0f, 0.0f};
        #pragma unroll 4
        for (int j = wv; j < i0; j += 4) {
            const v4f v4 = *(const v4f*)&spnd[j * RSTR + qoff];
            const v2f df = spi - (v2f){v4.x, v4.y};
            const v2f ex = (v2f){v4.z, v4.w} *
                (v2f){__builtin_amdgcn_logf(df.x), __builtin_amdgcn_logf(df.y)};
            r += (v2f){__builtin_amdgcn_exp2f(ex.x), __builtin_amdgcn_exp2f(ex.y)};
        }
        *(v2f*)&rbuf[wv * 128 + 2 * lane] = r;

        // ---- logs for NEXT tile into buf^1
        if (i0 + T < S) {
            const int rb = (i0 + T) * RSTR, lb = (buf ^ 1) * LTS;
            const v2f A = *(const v2f*)&spnd[rb + ro1d] - *(const v2f*)&spnd[rb + ro1j];
            *(v2f*)&ltri[lb + dst1] =
                (v2f){__builtin_amdgcn_logf(A.x), __builtin_amdgcn_logf(A.y)};
            if (ok2) {
                const v2f Bv = *(const v2f*)&spnd[rb + ro2d] - *(const v2f*)&spnd[rb + ro2j];
                *(v2f*)&ltri[lb + dst2] =
                    (v2f){__builtin_amdgcn_logf(Bv.x), __builtin_amdgcn_logf(Bv.y)};
            }
        }
        __syncthreads();   // barrier1: rect partials + ltri[buf] ready

        // ---- triangle: wave 0 resolves all 8 cols
        if (wv == 0) {
            v2f rt = r;
            rt += *(const v2f*)&rbuf[128 + 2 * lane];
            rt += *(const v2f*)&rbuf[256 + 2 * lane];
            rt += *(const v2f*)&rbuf[384 + 2 * lane];
            const int tb = buf * LTS + tribase;
            v2f t_ = {0.0f, 0.0f};
            #pragma unroll
            for (int j = 0; j < 15; ++j) {
                const v2f cur = t_ + rt;
                const v2f cn  = {fmaf(-c, cur.x, -a), fmaf(-c, cur.y, -a)}; // valid d=j
                const float snx = __int_as_float(
                    __builtin_amdgcn_ds_bpermute(bpa + 4 * j, __float_as_int(cn.x)));
                const float sny = __int_as_float(
                    __builtin_amdgcn_ds_bpermute(bpa + 4 * j, __float_as_int(cn.y)));
                const float* Lp = (j < d) ? &ltri[tb + 8 * j] : sent;
                const v2f L = *(const v2f*)Lp;           // sentinel: term -> 0
                t_ += (v2f){__builtin_amdgcn_exp2f(snx * L.x),
                            __builtin_amdgcn_exp2f(sny * L.y)};
            }
            const v2f sum = t_ + rt;                     // valid in every lane
            const v2f nd  = {fmaf(-c, sum.x, -a), fmaf(-c, sum.y, -a)};
            *(v2f*)&spnd[(i0 + d) * RSTR + qoff + 2] = nd;
            if (i0 + d > 0) {
                const float mx = __builtin_amdgcn_logf(sum.x) * ln2;
                const float my = __builtin_amdgcn_logf(sum.y) * ln2;
                const float ex = __builtin_amdgcn_exp2f((tau - mx) * k_out);
                const float ey = __builtin_amdgcn_exp2f((tau - my) * k_out);
                *(v2f*)&out[(size_t)(i0 + d - 1) * B + gc0 + 2 * pr] =
                    (v2f){__builtin_amdgcn_rcpf(1.0f + ex),
                          __builtin_amdgcn_rcpf(1.0f + ey)};
            }
        }
        __syncthreads();   // barrier2: nd visible to all waves
        buf ^= 1;
    }
}

extern "C" void kernel_launch(void* const* d_in, const int* in_sizes, int n_in,
                              void* d_out, int out_size, void* d_ws, size_t ws_size,
                              hipStream_t stream) {
    const float* sp = (const float*)d_in[0];
    const float* w  = (const float*)d_in[1];
    float*       o  = (float*)d_out;
    actr_kernel<<<dim3(B / CPB), dim3(256), 0, stream>>>(sp, w, o);
}

// Round 10
// 101.791 us; speedup vs baseline: 1.0025x; 1.0025x over previous
//
#include <hip/hip_runtime.h>

// ACT-R activation recurrence, v7b: triangle[t] overlapped with rect-old[t+1],
// race-free by construction (owner writes ONLY ndnew+out during PhaseB; spnd
// has no writers while any wave reads it concurrently).
// m[i] = log( sum_{j<i} ((sp_i-sp_j)*86400*h)^(-(c*exp(m_j)+a)) ), m[0]=-inf
// out[i-1] = 1/(1+exp((tau-m[i])/s)).  exp(m_j)==sum_j => nd_j = -(c*sum_j+a).
// (clamp dropped: diffs >= 0.1*86400*0.025 = 216 >> 1; nd < -a < 0 always.)
//
// Block: 256 thr = 4 waves, 8 cols (4 pairs); lane = d(0..15) x pair(0..3),
// v2f per lane. Grid 2048 -> 8 blocks/CU (32 waves/CU). Per tile t (i0=16t):
//  PhaseA (all): copy ndnew (tile t-1 decays) -> spnd nd-fields; strip rect
//          rows(t) over j in [i0-16,i0) (mod-4 by wave; nd read from ndnew);
//          logs[t]; racc -> rbuf.                                  barrier1.
//  PhaseB: owner wave (t&3): sum rbuf, transposed triangle (bpermute
//          broadcast, sentinel L=1e9 kills d<=j terms), write ndnew + sigmoid
//          out.  other waves: rect-old rows(t+1) over j in [0,i0) (mod-3) --
//          the bulk of the work, hiding the serial triangle.       barrier2.

typedef float v2f __attribute__((ext_vector_type(2)));
typedef float v4f __attribute__((ext_vector_type(4)));

constexpr int S    = 128;
constexpr int B    = 16384;
constexpr int T    = 16;
constexpr int CPB  = 8;     // cols per block (4 pairs)
constexpr int RSTR = 20;    // floats/row: 4 quads (sp0,sp1,nd0,nd1) + 4 pad
constexpr int LTS  = 960;   // ltri floats: 120 slots x (4 pairs x v2f)

__launch_bounds__(256, 8)
__global__ void actr_kernel(const float* __restrict__ sp,
                            const float* __restrict__ w,
                            float* __restrict__ out) {
    __shared__ float spnd[S * RSTR];   // 10240 B
    __shared__ float ltri[LTS];        //  3840 B
    __shared__ float rbuf[4 * 128];    //  2048 B
    __shared__ float ndnew[128];       //   512 B: [16 rows][4 quads][2]

    const int tid  = threadIdx.x;
    const int wv   = tid >> 6;
    const int lane = tid & 63;
    const int d    = lane & 15;
    const int pr   = lane >> 4;           // pair 0..3
    const int qoff = 4 * pr;
    const int gc0  = blockIdx.x * CPB;

    const float a = w[0], c = w[1], sv = w[2], tau = w[3], h = w[4];
    const float scale = 86400.0f * h;
    const float k_out = 1.44269504088896f / sv;   // log2(e)/s
    const float ln2   = 0.693147180559945f;

    // ---- stage sp*scale; sentinel pair in row0 pad
    for (int idx = tid; idx < S * CPB; idx += 256) {
        const int j = idx >> 3, cc = idx & 7;
        spnd[j * RSTR + 4 * (cc >> 1) + (cc & 1)] = sp[j * B + gc0 + cc] * scale;
    }
    if (tid < 2) spnd[16 + tid] = 1.0e9f;

    // ---- decode 2 log tasks: ids tid, tid+256 (of 480 = 120 slots x 4 pairs)
    int ro1d, ro1j, dst1, ro2d = 0, ro2j = 0, dst2 = 0;
    {
        int g = tid;
        #pragma unroll
        for (int k = 0; k < 2; ++k) {
            const int p = g >> 2, q = g & 3;
            int t = (int)((1.0f + __builtin_sqrtf(1.0f + 8.0f * (float)p)) * 0.5f);
            while (t * (t - 1) / 2 > p) --t;
            while ((t + 1) * t / 2 <= p) ++t;
            const int dd = t, jj = p - t * (t - 1) / 2;   // slot (dd,jj), jj<dd
            const int rd = dd * RSTR + 4 * q, rj = jj * RSTR + 4 * q;
            const int ds = p * 8 + 2 * q;
            if (k == 0) { ro1d = rd; ro1j = rj; dst1 = ds; }
            else        { ro2d = rd; ro2j = rj; dst2 = ds; }
            g += 256;
        }
    }
    const bool ok2 = tid < (480 - 256);
    __syncthreads();

    const int   bpa     = (lane & 0x30) * 4;        // bpermute byte base (lane 16*pr)
    const int   tribase = d * (d - 1) * 4 + 2 * pr; // slot-base*8 + 2*pr
    const float* sent   = &spnd[16];

    v2f racc = {0.0f, 0.0f};   // this wave's rect partial for the CURRENT tile

    for (int t = 0; t < S / T; ++t) {
        const int i0 = t * T;

        // ---- PhaseA ----
        if (t > 0) {
            // copy tile t-1 decays into spnd nd-fields (rows [i0-16, i0)).
            // writes nd bytes only; concurrent reads below touch sp bytes only.
            if (tid < 64) {
                const v2f nv = *(const v2f*)&ndnew[2 * tid];   // tid = row*4 + q
                *(v2f*)&spnd[(i0 - T + (tid >> 2)) * RSTR + 4 * (tid & 3) + 2] = nv;
            }
            // strip: rows i0+d, j in [i0-16, i0), residue wv (nd from ndnew)
            const v2f spiA = *(const v2f*)&spnd[(i0 + d) * RSTR + qoff];
            #pragma unroll
            for (int k = 0; k < 4; ++k) {
                const int j  = i0 - T + wv + 4 * k;
                const int jr = wv + 4 * k;
                const v2f sj = *(const v2f*)&spnd[j * RSTR + qoff];
                const v2f nj = *(const v2f*)&ndnew[jr * 8 + 2 * pr];
                const v2f df = spiA - sj;
                const v2f ex = nj *
                    (v2f){__builtin_amdgcn_logf(df.x), __builtin_amdgcn_logf(df.y)};
                racc += (v2f){__builtin_amdgcn_exp2f(ex.x), __builtin_amdgcn_exp2f(ex.y)};
            }
        }
        {   // logs[t]: decay-independent triangle logs for this tile
            const int rb = i0 * RSTR;
            const v2f A = *(const v2f*)&spnd[rb + ro1d] - *(const v2f*)&spnd[rb + ro1j];
            *(v2f*)&ltri[dst1] =
                (v2f){__builtin_amdgcn_logf(A.x), __builtin_amdgcn_logf(A.y)};
            if (ok2) {
                const v2f Bv = *(const v2f*)&spnd[rb + ro2d] - *(const v2f*)&spnd[rb + ro2j];
                *(v2f*)&ltri[dst2] =
                    (v2f){__builtin_amdgcn_logf(Bv.x), __builtin_amdgcn_logf(Bv.y)};
            }
        }
        *(v2f*)&rbuf[wv * 128 + 2 * lane] = racc;
        __syncthreads();   // barrier1: rbuf + ltri + nd-copy ready

        const int ow = t & 3;   // triangle owner rotates
        if (wv == ow) {
            // ---- triangle: resolve all 8 cols for tile t (writes ndnew only)
            v2f rt = *(const v2f*)&rbuf[2 * lane];
            rt += *(const v2f*)&rbuf[128 + 2 * lane];
            rt += *(const v2f*)&rbuf[256 + 2 * lane];
            rt += *(const v2f*)&rbuf[384 + 2 * lane];
            v2f t_ = {0.0f, 0.0f};
            #pragma unroll
            for (int j = 0; j < 15; ++j) {
                const v2f cur = t_ + rt;
                const v2f cn  = {fmaf(-c, cur.x, -a), fmaf(-c, cur.y, -a)}; // valid d=j
                const float snx = __int_as_float(
                    __builtin_amdgcn_ds_bpermute(bpa + 4 * j, __float_as_int(cn.x)));
                const float sny = __int_as_float(
                    __builtin_amdgcn_ds_bpermute(bpa + 4 * j, __float_as_int(cn.y)));
                const float* Lp = (j < d) ? &ltri[tribase + 8 * j] : sent;
                const v2f L = *(const v2f*)Lp;           // sentinel: term -> 0
                t_ += (v2f){__builtin_amdgcn_exp2f(snx * L.x),
                            __builtin_amdgcn_exp2f(sny * L.y)};
            }
            const v2f sum = t_ + rt;                     // valid in every lane
            const v2f nd  = {fmaf(-c, sum.x, -a), fmaf(-c, sum.y, -a)};
            *(v2f*)&ndnew[d * 8 + 2 * pr] = nd;
            if (i0 + d > 0) {
                const float mx = __builtin_amdgcn_logf(sum.x) * ln2;
                const float my = __builtin_amdgcn_logf(sum.y) * ln2;
                const float ex = __builtin_amdgcn_exp2f((tau - mx) * k_out);
                const float ey = __builtin_amdgcn_exp2f((tau - my) * k_out);
                *(v2f*)&out[(size_t)(i0 + d - 1) * B + gc0 + 2 * pr] =
                    (v2f){__builtin_amdgcn_rcpf(1.0f + ex),
                          __builtin_amdgcn_rcpf(1.0f + ey)};
            }
            racc = (v2f){0.0f, 0.0f};   // owner contributes only strip next tile
        } else if (i0 + T < S) {
            // ---- rect-old for tile t+1: rows i0+16+d, j in [0, i0), mod-3 split
            const int rk = (wv - ow - 1) & 3;            // 0,1,2
            const v2f spiB = *(const v2f*)&spnd[(i0 + T + d) * RSTR + qoff];
            v2f rn = {0.0f, 0.0f};
            #pragma unroll 4
            for (int j = rk; j < i0; j += 3) {
                const v4f v4 = *(const v4f*)&spnd[j * RSTR + qoff];
                const v2f df = spiB - (v2f){v4.x, v4.y};
                const v2f ex = (v2f){v4.z, v4.w} *
                    (v2f){__builtin_amdgcn_logf(df.x), __builtin_amdgcn_logf(df.y)};
                rn += (v2f){__builtin_amdgcn_exp2f(ex.x), __builtin_amdgcn_exp2f(ex.y)};
            }
            racc = rn;
        }
        __syncthreads();   // barrier2: ndnew[t] visible for next PhaseA
    }
}

extern "C" void kernel_launch(void* const* d_in, const int* in_sizes, int n_in,
                              void* d_out, int out_size, void* d_ws, size_t ws_size,
                              hipStream_t stream) {
    const float* sp = (const float*)d_in[0];
    const float* w  = (const float*)d_in[1];
    float*       o  = (float*)d_out;
    actr_kernel<<<dim3(B / CPB), dim3(256), 0, stream>>>(sp, w, o);
}